// Round 6
// baseline (985.548 us; speedup 1.0000x reference)
//
#include <hip/hip_runtime.h>
#include <cstdint>
#include <cstddef>

// Problem constants (fixed by the reference)
#define B_ROWS 8192
#define E_EXP  8

typedef unsigned short ushort_t;
typedef short bf16x8 __attribute__((ext_vector_type(8)));
typedef float f32x4  __attribute__((ext_vector_type(4)));

__device__ __forceinline__ ushort_t f2b(float f) {
  union { float f; unsigned int i; } v; v.f = f;
  unsigned int u = v.i;
  unsigned int r = (u + 0x7fffu + ((u >> 16) & 1u)) >> 16;
  return (ushort_t)r;
}
__device__ __forceinline__ float eluf(float x) {
  return x > 0.f ? x : (__expf(x) - 1.f);
}

// ---------------------------------------------------------------------------
// Weight transpose + fp32->bf16: w flat [R][C] -> wT [C][R] bf16.
// ---------------------------------------------------------------------------
__global__ void transpose_k(const float* __restrict__ src,
                            ushort_t* __restrict__ dst, int R, int C) {
  __shared__ ushort_t tile[64][65];
  int c0 = blockIdx.x * 64, r0 = blockIdx.y * 64;
  int x = threadIdx.x, y = threadIdx.y;
#pragma unroll
  for (int i = 0; i < 4; ++i)
    tile[y + 16 * i][x] = f2b(src[(size_t)(r0 + y + 16 * i) * C + c0 + x]);
  __syncthreads();
#pragma unroll
  for (int i = 0; i < 4; ++i)
    dst[(size_t)(c0 + y + 16 * i) * R + r0 + x] = tile[x][y + 16 * i];
}

// ---------------------------------------------------------------------------
// Gating MLP (pure fp32). Emits:
//   coeff[b][e]  softmax probs
//   rat1[b][e]   full-chain Horner scales (e<7: c_e/c_{e+1}; e=7: c_7)
//   rat2[b][e]   2-way split {0-3},{4-7}: e in {3,7}: c_e; else ratio
// ---------------------------------------------------------------------------
__global__ __launch_bounds__(128) void gate_k(
    const float* __restrict__ z, const float* __restrict__ c,
    const float* __restrict__ g0w, const float* __restrict__ g0b,
    const float* __restrict__ g1w, const float* __restrict__ g1b,
    const float* __restrict__ g2w, const float* __restrict__ g2b,
    float* __restrict__ coeff, float* __restrict__ rat1,
    float* __restrict__ rat2) {
  __shared__ float xs[4][320];
  __shared__ float h1[4][128];
  __shared__ float h2[4][128];
  __shared__ float lg[4][8];
  __shared__ float pr[4][8];
  int t = threadIdx.x;
  int r0 = blockIdx.x * 4;
  for (int idx = t; idx < 4 * 320; idx += 128) {
    int r = idx / 320, j = idx % 320;
    xs[r][j] = (j < 64) ? z[(size_t)(r0 + r) * 64 + j]
                        : c[(size_t)(r0 + r) * 256 + j - 64];
  }
  __syncthreads();
  {
    float bb = g0b[t];
    float a0 = bb, a1 = bb, a2 = bb, a3 = bb;
    for (int j = 0; j < 320; ++j) {
      float wv = g0w[j * 128 + t];
      a0 += xs[0][j] * wv; a1 += xs[1][j] * wv;
      a2 += xs[2][j] * wv; a3 += xs[3][j] * wv;
    }
    h1[0][t] = eluf(a0); h1[1][t] = eluf(a1);
    h1[2][t] = eluf(a2); h1[3][t] = eluf(a3);
  }
  __syncthreads();
  {
    float bb = g1b[t];
    float a0 = bb, a1 = bb, a2 = bb, a3 = bb;
    for (int j = 0; j < 128; ++j) {
      float wv = g1w[j * 128 + t];
      a0 += h1[0][j] * wv; a1 += h1[1][j] * wv;
      a2 += h1[2][j] * wv; a3 += h1[3][j] * wv;
    }
    h2[0][t] = eluf(a0); h2[1][t] = eluf(a1);
    h2[2][t] = eluf(a2); h2[3][t] = eluf(a3);
  }
  __syncthreads();
  if (t < 32) {
    int r = t >> 3, e = t & 7;
    float a = g2b[e];
    for (int j = 0; j < 128; ++j) a += h2[r][j] * g2w[j * 8 + e];
    lg[r][e] = a;
  }
  __syncthreads();
  if (t < 32) {
    int r = t >> 3, e = t & 7;
    float mx = lg[r][0];
#pragma unroll
    for (int i = 1; i < 8; ++i) mx = fmaxf(mx, lg[r][i]);
    float s = 0.f;
#pragma unroll
    for (int i = 0; i < 8; ++i) s += __expf(lg[r][i] - mx);
    float p = __expf(lg[r][e] - mx) / s;
    coeff[(size_t)(r0 + r) * 8 + e] = p;
    pr[r][e] = p;
  }
  __syncthreads();
  if (t < 32) {
    int r = t >> 3, e = t & 7;
    float pe = pr[r][e];
    float ratio = (e < 7) ? pe / fmaxf(pr[r][e + 1], 1e-30f) : pe;
    rat1[(size_t)(r0 + r) * 8 + e] = ratio;
    rat2[(size_t)(r0 + r) * 8 + e] = (e == 3 || e == 7) ? pe : ratio;
  }
}

// ---------------------------------------------------------------------------
// LayerNorm over concat([z_row, prev_row]) -> out [B][J] bf16.
//   cf != null : prev = elu(p0 + sum_e cf[row,e]*bias[e,:])  (post-GEMM layers)
//   cf == null : prev = p0 raw (layer-0 path reading c)
// ---------------------------------------------------------------------------
__global__ __launch_bounds__(128) void ln_concat_k(
    const float* __restrict__ z, const float* __restrict__ p0,
    const float* __restrict__ cf, const float* __restrict__ bias,
    ushort_t* __restrict__ out, int Pw, int J) {
  int row = blockIdx.x, t = threadIdx.x;
  float vals[9];
  int n = (J + 127) >> 7;
  float cr[8];
  if (cf) {
#pragma unroll
    for (int e = 0; e < 8; ++e) cr[e] = cf[(size_t)row * 8 + e];
  }
  float s = 0.f, s2 = 0.f;
  for (int k = 0; k < n; ++k) {
    int i = t + (k << 7);
    float x = 0.f;
    if (i < J) {
      if (i < 64) {
        x = z[(size_t)row * 64 + i];
      } else if (cf) {
        int j = i - 64;
        float v = p0[(size_t)row * Pw + j];
#pragma unroll
        for (int e = 0; e < 8; ++e) v += cr[e] * bias[(size_t)e * Pw + j];
        x = eluf(v);
      } else {
        x = p0[(size_t)row * Pw + i - 64];
      }
    }
    vals[k] = x; s += x; s2 += x * x;
  }
  for (int off = 32; off > 0; off >>= 1) {
    s += __shfl_down(s, off);
    s2 += __shfl_down(s2, off);
  }
  __shared__ float red[4];
  int wid = t >> 6, lane = t & 63;
  if (lane == 0) { red[wid * 2] = s; red[wid * 2 + 1] = s2; }
  __syncthreads();
  float S = red[0] + red[2], S2 = red[1] + red[3];
  float inv = 1.f / (float)J;
  float m = S * inv;
  float var = S2 * inv - m * m;
  float rstd = rsqrtf(var + 1e-5f);
  for (int k = 0; k < n; ++k) {
    int i = t + (k << 7);
    if (i < J) out[(size_t)row * J + i] = f2b((vals[k] - m) * rstd);
  }
}

// ---------------------------------------------------------------------------
// Fused MoE GEMM, round 12: 128x128 tile, 2 BLOCKS PER CU (cross-block TLP).
//
// Round-4 post-mortem: per-phase double-barrier lockstep NEUTRAL at 40%
// MfmaUtil. Cycle audit: per phase, MFMA window (621 cyc/CU) and LDS-read
// service (~700-900 cyc) run back-to-back = 1428 cyc measured — fully
// SERIAL. One barrier-synced block cannot overlap its own read and MFMA
// windows. Fix: two mutually-unsynchronized blocks per CU (m114 mechanism:
// separate waves co-issue to MFMA + LDS pipes with time=max not sum). When
// block A is in its read window, block B is in its MFMA window.
//
// 128x128 tile, 256 thr / 4 waves (2Mx2N, per-wave 64x64, acc[4][4]=64
// VGPR), BK=64 double-buffered, counted vmcnt(8) (round-3 proven schedule).
// LDS: A 2x16KB + W 2x16KB + scales 4.5KB = 68.5KB -> exactly 2 blocks/CU.
// Grid 512 blocks = 2/CU. Full 8-expert Horner layers 0-2 (no partials);
// layer 3 2-way expert split (rat2 + combine2). Bytes/FLOP unchanged vs
// round 4 (stage 7.6 B/kF, reads 15.3 B/kF — LDS stays non-binding).
// W offsets linear across experts; A col resets per expert. XCD = bt%8.
// ---------------------------------------------------------------------------
__device__ __forceinline__ void gload16(const void* g, void* l) {
  __builtin_amdgcn_global_load_lds(
      (const __attribute__((address_space(1))) void*)g,
      (__attribute__((address_space(3))) void*)l, 16, 0, 0);
}

__global__ __launch_bounds__(256, 2) void moe_gemm_k(
    const ushort_t* __restrict__ inp,   // [B][J] bf16 (LN'd concat)
    const ushort_t* __restrict__ wT,    // [K][E*J] bf16 (pre-transposed)
    const float* __restrict__ scales,   // [B][8] Horner boundary scales
    float* __restrict__ outp,           // [nez][B][K] fp32 (partials if split)
    int J, int K, int ne) {
  const int Kd = E_EXP * J;
  const int nj = J >> 6;        // BK=64 tiles per expert
  const int nt = ne * nj;       // total K-tiles for this block's expert range
  // 16 blocks of 1KB per buffer: block bi covers rows g*16..+16 (g=bi&7),
  // k-cols c*32..+32 (c=bi>>3); lane l = row (l&15), col-chunk (l>>4)*8.
  __shared__ short As[2][16 * 512];    // 32KB
  __shared__ short Wsm[2][16 * 512];   // 32KB
  __shared__ float scale_s[128 * 9];   // [row][e] stride 9 (bank pad) 4.5KB

  const int t = threadIdx.x;
  const int w = t >> 6, l = t & 63;
  const int wm = w >> 1, wn = w & 1;   // 2M x 2N wave layout
  const int bt = blockIdx.x, ct = blockIdx.y, ez = blockIdx.z;
  const int e0 = ez * ne;
  outp += (size_t)ez * (size_t)B_ROWS * (size_t)K;

#pragma unroll
  for (int i = 0; i < 4; ++i) {
    int idx = t + (i << 8);  // 0..1023
    int rw = idx >> 3, e = idx & 7;
    scale_s[rw * 9 + e] = scales[(size_t)(bt * 128 + rw) * 8 + e];
  }

  // Stage bases: wave w owns LDS blocks {r*4+w : r=0..3} for A and W.
  size_t abase[4], wbase[4];
#pragma unroll
  for (int r = 0; r < 4; ++r) {
    int bi = r * 4 + w, g = bi & 7, c = bi >> 3;
    abase[r] = (size_t)(bt * 128 + g * 16 + (l & 15)) * J +
               (c * 32 + (l >> 4) * 8);
    wbase[r] = (size_t)(ct * 128 + g * 16 + (l & 15)) * Kd + (size_t)e0 * J +
               (c * 32 + (l >> 4) * 8);
  }
  int acol = 0, wcol = 0, sjt = 0;  // stage-side counters (next tile)

  auto stage = [&](int nb) {
#pragma unroll
    for (int r = 0; r < 4; ++r) {
      gload16(inp + abase[r] + acol, &As[nb][(r * 4 + w) * 512]);
      gload16(wT + wbase[r] + wcol, &Wsm[nb][(r * 4 + w) * 512]);
    }
    wcol += 64;
    if (++sjt == nj) { sjt = 0; acol = 0; } else { acol += 64; }
  };

  f32x4 acc[4][4];
#pragma unroll
  for (int q = 0; q < 4; ++q)
#pragma unroll
    for (int fn = 0; fn < 4; ++fn) acc[q][fn] = (f32x4){0.f, 0.f, 0.f, 0.f};

  // prologue: tile 0 into buf 0; full drain once (also publishes scale_s).
  stage(0);
  __syncthreads();

  int cjt = 0, cle = 0;  // compute-side counters
  for (int tp = 0; tp < nt; ++tp) {
    const int b = tp & 1;
    if (tp + 1 < nt) {
      stage(b ^ 1);  // issue next tile's 8 loads (stay in flight past barrier)
      asm volatile("s_waitcnt vmcnt(8)" ::: "memory");  // wait CURRENT tile's 8
    } else {
      asm volatile("s_waitcnt vmcnt(0)" ::: "memory");
    }
    asm volatile("s_barrier" ::: "memory");   // raw barrier: no drain
    {
      const short* Ab = As[b];
      const short* Wb = Wsm[b];
      bf16x8 af[4], bf[4];
#pragma unroll
      for (int ks = 0; ks < 2; ++ks) {
#pragma unroll
        for (int fn = 0; fn < 4; ++fn)
          bf[fn] = *(const bf16x8*)(Wb + (ks * 8 + wn * 4 + fn) * 512 + l * 8);
#pragma unroll
        for (int q = 0; q < 4; ++q)
          af[q] = *(const bf16x8*)(Ab + (ks * 8 + wm * 4 + q) * 512 + l * 8);
        __builtin_amdgcn_s_setprio(1);
#pragma unroll
        for (int q = 0; q < 4; ++q)
#pragma unroll
          for (int fn = 0; fn < 4; ++fn)
            acc[q][fn] = __builtin_amdgcn_mfma_f32_16x16x32_bf16(
                af[q], bf[fn], acc[q][fn], 0, 0, 0);
        __builtin_amdgcn_s_setprio(0);
      }
    }
    // Horner boundary rescale at expert end
    if (++cjt == nj) {
      cjt = 0;
      int e = e0 + cle;
      ++cle;
#pragma unroll
      for (int q = 0; q < 4; ++q) {
        int rbase = wm * 64 + q * 16 + ((l >> 4) << 2);
#pragma unroll
        for (int rr = 0; rr < 4; ++rr) {
          float rv = scale_s[(rbase + rr) * 9 + e];
#pragma unroll
          for (int fn = 0; fn < 4; ++fn) acc[q][fn][rr] *= rv;
        }
      }
    }
    asm volatile("s_barrier" ::: "memory");   // all reads of buf b done
  }

  // epilogue: raw fp32 store (bias/ELU fused downstream)
#pragma unroll
  for (int q = 0; q < 4; ++q) {
#pragma unroll
    for (int rr = 0; rr < 4; ++rr) {
      int row = wm * 64 + q * 16 + ((l >> 4) << 2) + rr;
      size_t orow = (size_t)(bt * 128 + row) * K + ct * 128;
#pragma unroll
      for (int fn = 0; fn < 4; ++fn) {
        int col = wn * 64 + fn * 16 + (l & 15);
        outp[orow + col] = acc[q][fn][rr];
      }
    }
  }
}

// ---------------------------------------------------------------------------
// Final combine for layer 3 (2-way expert split, K=512, no activation):
//   out = p0 + p1 + coeff@bias
// ---------------------------------------------------------------------------
__global__ __launch_bounds__(256) void combine2_k(
    const float* __restrict__ pb, const float* __restrict__ cf,
    const float* __restrict__ bias, float* __restrict__ out, int K) {
  size_t i4 = (size_t)blockIdx.x * 256 + threadIdx.x;
  size_t total = (size_t)B_ROWS * (size_t)K;
  size_t base = i4 * 4;
  if (base >= total) return;
  int row = (int)(base / (size_t)K);
  int col = (int)(base % (size_t)K);
  size_t s4 = total >> 2;
  const f32x4* p4 = (const f32x4*)pb;
  f32x4 v = p4[i4] + p4[i4 + s4];
#pragma unroll
  for (int e = 0; e < 8; ++e) {
    float ce = cf[(size_t)row * 8 + e];
    f32x4 bv = *(const f32x4*)(bias + (size_t)e * K + col);
    v += ce * bv;
  }
  ((f32x4*)out)[i4] = v;
}

// ---------------------------------------------------------------------------
extern "C" void kernel_launch(void* const* d_in, const int* in_sizes, int n_in,
                              void* d_out, int out_size, void* d_ws, size_t ws_size,
                              hipStream_t stream) {
  const float* z   = (const float*)d_in[0];
  const float* c   = (const float*)d_in[1];
  const float* g0w = (const float*)d_in[2];
  const float* g0b = (const float*)d_in[3];
  const float* g1w = (const float*)d_in[4];
  const float* g1b = (const float*)d_in[5];
  const float* g2w = (const float*)d_in[6];
  const float* g2b = (const float*)d_in[7];
  const float* w0  = (const float*)d_in[8];
  const float* b0  = (const float*)d_in[9];
  const float* w1  = (const float*)d_in[10];
  const float* b1  = (const float*)d_in[11];
  const float* w2  = (const float*)d_in[12];
  const float* b2  = (const float*)d_in[13];
  const float* w3  = (const float*)d_in[14];
  const float* b3  = (const float*)d_in[15];

  char* ws = (char*)d_ws;
  size_t o = 0;
  auto alloc = [&](size_t bytes) {
    void* p = ws + o;
    o += (bytes + 255) & ~(size_t)255;
    return p;
  };
  ushort_t* wT0 = (ushort_t*)alloc((size_t)2560 * 1024 * 2);
  ushort_t* wT1 = (ushort_t*)alloc((size_t)8704 * 1024 * 2);
  ushort_t* wT2 = (ushort_t*)alloc((size_t)8704 * 1024 * 2);
  ushort_t* wT3 = (ushort_t*)alloc((size_t)8704 * 512 * 2);
  float*    cf   = (float*)alloc((size_t)B_ROWS * 8 * 4);
  float*    rat1 = (float*)alloc((size_t)B_ROWS * 8 * 4);
  float*    rat2 = (float*)alloc((size_t)B_ROWS * 8 * 4);
  ushort_t* inp  = (ushort_t*)alloc((size_t)B_ROWS * 1088 * 2);
  float*    hb   = (float*)alloc((size_t)B_ROWS * 1024 * 4);
  float*    pb   = (float*)alloc((size_t)2 * B_ROWS * 512 * 4);

  dim3 tb(64, 16);
  transpose_k<<<dim3(1024 / 64, 2560 / 64), tb, 0, stream>>>(w0, wT0, 2560, 1024);
  transpose_k<<<dim3(1024 / 64, 8704 / 64), tb, 0, stream>>>(w1, wT1, 8704, 1024);
  transpose_k<<<dim3(1024 / 64, 8704 / 64), tb, 0, stream>>>(w2, wT2, 8704, 1024);
  transpose_k<<<dim3(512 / 64, 8704 / 64), tb, 0, stream>>>(w3, wT3, 8704, 512);

  gate_k<<<B_ROWS / 4, 128, 0, stream>>>(z, c, g0w, g0b, g1w, g1b, g2w, g2b,
                                         cf, rat1, rat2);

  // layer 0: J=320, K=1024, full 8-expert Horner, grid 64x8 = 512 = 2/CU
  ln_concat_k<<<B_ROWS, 128, 0, stream>>>(z, c, nullptr, nullptr, inp, 256, 320);
  moe_gemm_k<<<dim3(64, 8, 1), 256, 0, stream>>>(inp, wT0, rat1, hb, 320, 1024, 8);
  // layer 1: J=1088, K=1024 (ln fuses b0-mix + elu)
  ln_concat_k<<<B_ROWS, 128, 0, stream>>>(z, hb, cf, b0, inp, 1024, 1088);
  moe_gemm_k<<<dim3(64, 8, 1), 256, 0, stream>>>(inp, wT1, rat1, hb, 1088, 1024, 8);
  // layer 2
  ln_concat_k<<<B_ROWS, 128, 0, stream>>>(z, hb, cf, b1, inp, 1024, 1088);
  moe_gemm_k<<<dim3(64, 8, 1), 256, 0, stream>>>(inp, wT2, rat1, hb, 1088, 1024, 8);
  // layer 3: J=1088, K=512, 2-way expert split, grid 64x4x2 = 512
  ln_concat_k<<<B_ROWS, 128, 0, stream>>>(z, hb, cf, b2, inp, 1024, 1088);
  moe_gemm_k<<<dim3(64, 4, 2), 256, 0, stream>>>(inp, wT3, rat2, pb, 1088, 512, 4);
  combine2_k<<<(B_ROWS * 512) / 1024, 256, 0, stream>>>(pb, cf, b3,
                                                        (float*)d_out, 512);
}

// Round 7
// 763.644 us; speedup vs baseline: 1.2906x; 1.2906x over previous
//
#include <hip/hip_runtime.h>
#include <cstdint>
#include <cstddef>

// Problem constants (fixed by the reference)
#define B_ROWS 8192
#define E_EXP  8

typedef unsigned short ushort_t;
typedef short bf16x8 __attribute__((ext_vector_type(8)));
typedef float f32x4  __attribute__((ext_vector_type(4)));

__device__ __forceinline__ ushort_t f2b(float f) {
  union { float f; unsigned int i; } v; v.f = f;
  unsigned int u = v.i;
  unsigned int r = (u + 0x7fffu + ((u >> 16) & 1u)) >> 16;
  return (ushort_t)r;
}
__device__ __forceinline__ float eluf(float x) {
  return x > 0.f ? x : (__expf(x) - 1.f);
}

// ---------------------------------------------------------------------------
// Weight transpose + fp32->bf16: w flat [R][C] -> wT [C][R] bf16.
// ---------------------------------------------------------------------------
__global__ void transpose_k(const float* __restrict__ src,
                            ushort_t* __restrict__ dst, int R, int C) {
  __shared__ ushort_t tile[64][65];
  int c0 = blockIdx.x * 64, r0 = blockIdx.y * 64;
  int x = threadIdx.x, y = threadIdx.y;
#pragma unroll
  for (int i = 0; i < 4; ++i)
    tile[y + 16 * i][x] = f2b(src[(size_t)(r0 + y + 16 * i) * C + c0 + x]);
  __syncthreads();
#pragma unroll
  for (int i = 0; i < 4; ++i)
    dst[(size_t)(c0 + y + 16 * i) * R + r0 + x] = tile[x][y + 16 * i];
}

// ---------------------------------------------------------------------------
// Gating MLP (pure fp32). Emits:
//   coeff[b][e]  softmax probs
//   rat2[b][e]   2-way split {0-3},{4-7}: e in {3,7}: c_e; else c_e/c_{e+1}
//   rat4[b][e]   4-way split {0,1}..{6,7}: e odd: c_e; e even: c_e/c_{e+1}
// ---------------------------------------------------------------------------
__global__ __launch_bounds__(128) void gate_k(
    const float* __restrict__ z, const float* __restrict__ c,
    const float* __restrict__ g0w, const float* __restrict__ g0b,
    const float* __restrict__ g1w, const float* __restrict__ g1b,
    const float* __restrict__ g2w, const float* __restrict__ g2b,
    float* __restrict__ coeff, float* __restrict__ rat2,
    float* __restrict__ rat4) {
  __shared__ float xs[4][320];
  __shared__ float h1[4][128];
  __shared__ float h2[4][128];
  __shared__ float lg[4][8];
  __shared__ float pr[4][8];
  int t = threadIdx.x;
  int r0 = blockIdx.x * 4;
  for (int idx = t; idx < 4 * 320; idx += 128) {
    int r = idx / 320, j = idx % 320;
    xs[r][j] = (j < 64) ? z[(size_t)(r0 + r) * 64 + j]
                        : c[(size_t)(r0 + r) * 256 + j - 64];
  }
  __syncthreads();
  {
    float bb = g0b[t];
    float a0 = bb, a1 = bb, a2 = bb, a3 = bb;
    for (int j = 0; j < 320; ++j) {
      float wv = g0w[j * 128 + t];
      a0 += xs[0][j] * wv; a1 += xs[1][j] * wv;
      a2 += xs[2][j] * wv; a3 += xs[3][j] * wv;
    }
    h1[0][t] = eluf(a0); h1[1][t] = eluf(a1);
    h1[2][t] = eluf(a2); h1[3][t] = eluf(a3);
  }
  __syncthreads();
  {
    float bb = g1b[t];
    float a0 = bb, a1 = bb, a2 = bb, a3 = bb;
    for (int j = 0; j < 128; ++j) {
      float wv = g1w[j * 128 + t];
      a0 += h1[0][j] * wv; a1 += h1[1][j] * wv;
      a2 += h1[2][j] * wv; a3 += h1[3][j] * wv;
    }
    h2[0][t] = eluf(a0); h2[1][t] = eluf(a1);
    h2[2][t] = eluf(a2); h2[3][t] = eluf(a3);
  }
  __syncthreads();
  if (t < 32) {
    int r = t >> 3, e = t & 7;
    float a = g2b[e];
    for (int j = 0; j < 128; ++j) a += h2[r][j] * g2w[j * 8 + e];
    lg[r][e] = a;
  }
  __syncthreads();
  if (t < 32) {
    int r = t >> 3, e = t & 7;
    float mx = lg[r][0];
#pragma unroll
    for (int i = 1; i < 8; ++i) mx = fmaxf(mx, lg[r][i]);
    float s = 0.f;
#pragma unroll
    for (int i = 0; i < 8; ++i) s += __expf(lg[r][i] - mx);
    float p = __expf(lg[r][e] - mx) / s;
    coeff[(size_t)(r0 + r) * 8 + e] = p;
    pr[r][e] = p;
  }
  __syncthreads();
  if (t < 32) {
    int r = t >> 3, e = t & 7;
    float pe = pr[r][e];
    float ratio = (e < 7) ? pe / fmaxf(pr[r][e + 1], 1e-30f) : pe;
    rat2[(size_t)(r0 + r) * 8 + e] = (e == 3 || e == 7) ? pe : ratio;
    rat4[(size_t)(r0 + r) * 8 + e] = (e & 1) ? pe : ratio;
  }
}

// ---------------------------------------------------------------------------
// LayerNorm over concat([z_row, prev_row]) -> out [B][J] bf16.
//   p1 != null : prev = elu(p0 + p1 + sum_e cf[row,e]*bias[e,:])
//   p1 == null : prev = p0 raw (layer-0 path reading c)
// ---------------------------------------------------------------------------
__global__ __launch_bounds__(128) void ln_concat_k(
    const float* __restrict__ z, const float* __restrict__ p0,
    const float* __restrict__ p1, const float* __restrict__ cf,
    const float* __restrict__ bias, ushort_t* __restrict__ out,
    int Pw, int J) {
  int row = blockIdx.x, t = threadIdx.x;
  float vals[9];
  int n = (J + 127) >> 7;
  float cr[8];
  if (p1) {
#pragma unroll
    for (int e = 0; e < 8; ++e) cr[e] = cf[(size_t)row * 8 + e];
  }
  float s = 0.f, s2 = 0.f;
  for (int k = 0; k < n; ++k) {
    int i = t + (k << 7);
    float x = 0.f;
    if (i < J) {
      if (i < 64) {
        x = z[(size_t)row * 64 + i];
      } else if (p1) {
        int j = i - 64;
        float v = p0[(size_t)row * Pw + j] + p1[(size_t)row * Pw + j];
#pragma unroll
        for (int e = 0; e < 8; ++e) v += cr[e] * bias[(size_t)e * Pw + j];
        x = eluf(v);
      } else {
        x = p0[(size_t)row * Pw + i - 64];
      }
    }
    vals[k] = x; s += x; s2 += x * x;
  }
  for (int off = 32; off > 0; off >>= 1) {
    s += __shfl_down(s, off);
    s2 += __shfl_down(s2, off);
  }
  __shared__ float red[4];
  int wid = t >> 6, lane = t & 63;
  if (lane == 0) { red[wid * 2] = s; red[wid * 2 + 1] = s2; }
  __syncthreads();
  float S = red[0] + red[2], S2 = red[1] + red[3];
  float inv = 1.f / (float)J;
  float m = S * inv;
  float var = S2 * inv - m * m;
  float rstd = rsqrtf(var + 1e-5f);
  for (int k = 0; k < n; ++k) {
    int i = t + (k << 7);
    if (i < J) out[(size_t)row * J + i] = f2b((vals[k] - m) * rstd);
  }
}

// ---------------------------------------------------------------------------
// Fused MoE GEMM, round 13: 256x256 tile + REGISTER FRAG PIPELINE,
// single barrier per K-tile, whole-tile-ahead staging.
//
// Round-5 post-mortem: 128²+2blk/CU REGRESSED (270us) — smaller per-phase
// MFMA work put us back latency-bound; cross-block TLP didn't materialize.
// Reverted to round-3 base (159.5us, MfmaUtil 40%). Its cycle audit:
// 5630 cyc/K-tile = MFMA floor 2483 + LDS floor ~2760 run SERIALLY (each
// MFMA cluster's ds_reads immediately precede it). Fix: issue each phase's
// ds_reads one phase EARLY (register double-buffer of frags) so the SIMD
// issues MFMA while LDS serves the next frags -> per-tile ~max(2483,2900).
// To keep mid-tile k1-half reads legal with ONE barrier/K-tile, ALL 8 stage
// loads for tile tp+1 issue at the TOP of tile tp; the tile-end vmcnt(0)
// then drains loads issued ~3000 cyc earlier (~free, unlike round-1's
// drain-of-just-issued). Schedule per K-tile (buf b, 2Mx4N waves, 128x64):
//   stage ALL 8 loads (tile tp+1 -> buf nb)
//   read a1=A(k0,m4-7)          ; MFMA M0 (a0 x b0 -> acc[0..3])
//   read b1=B(k1), a0=A(k1,m0-3); MFMA M1 (a1 x b0 -> acc[4..7])
//   read a1=A(k1,m4-7)          ; MFMA M2 (a0 x b1 -> acc[0..3])
//                                 MFMA M3 (a1 x b1 -> acc[4..7])
//   [expert-boundary Horner rescale]
//   vmcnt(0); s_barrier
//   read b0=B(k0'), a0=A(k0',m0-3) from buf nb   (next tile's M0 operands)
//
// LDS: A 2x2x16KB + W 2x2x16KB = 128KB + scales 9KB -> 1 block/CU.
// Grid 256 = 1/CU via expert split: layers 0-2 ez=2 (rat2, partials
// combined in ln_concat_k), layer 3 ez=4 (rat4, combine4_k). XCD = bt%8.
// ---------------------------------------------------------------------------
__device__ __forceinline__ void gload16(const void* g, void* l) {
  __builtin_amdgcn_global_load_lds(
      (const __attribute__((address_space(1))) void*)g,
      (__attribute__((address_space(3))) void*)l, 16, 0, 0);
}

#define RD_B(dst, Wb)                                                      \
  _Pragma("unroll") for (int fn = 0; fn < 4; ++fn) dst[fn] =               \
      *(const bf16x8*)((Wb) + (wn * 4 + fn) * 512 + l * 8);

#define RD_A(dst, Ab, MB)                                                  \
  _Pragma("unroll") for (int q = 0; q < 4; ++q) dst[q] =                   \
      *(const bf16x8*)((Ab) + (wm * 8 + (MB) + q) * 512 + l * 8);

#define MM(MB, AA, BB)                                                     \
  __builtin_amdgcn_s_setprio(1);                                           \
  _Pragma("unroll") for (int q = 0; q < 4; ++q)                            \
      _Pragma("unroll") for (int fn = 0; fn < 4; ++fn) acc[(MB) + q][fn] = \
          __builtin_amdgcn_mfma_f32_16x16x32_bf16(AA[q], BB[fn],           \
                                                  acc[(MB) + q][fn], 0, 0, 0); \
  __builtin_amdgcn_s_setprio(0);

__global__ __launch_bounds__(512, 2) void moe_gemm_k(
    const ushort_t* __restrict__ inp,   // [B][J] bf16 (LN'd concat)
    const ushort_t* __restrict__ wT,    // [K][E*J] bf16 (pre-transposed)
    const float* __restrict__ scales,   // [B][8] Horner boundary scales
    float* __restrict__ outp,           // [nez][B][K] fp32 partials
    int J, int K, int ne) {
  const int Kd = E_EXP * J;
  const int nj = J >> 6;        // BK=64 tiles per expert
  const int nt = ne * nj;       // total K-tiles for this block's expert range
  __shared__ short As[2][2][16 * 512];   // [buf][ks][g*512 + l*8]  64KB
  __shared__ short Wsm[2][2][16 * 512];  // [buf][ks][h*512 + l*8]  64KB
  __shared__ float scale_s[256 * 9];     // [row][e] stride 9 (bank pad)

  const int t = threadIdx.x;
  const int w = t >> 6, l = t & 63;
  const int wm = w >> 2, wn = w & 3;     // 2M x 4N wave layout
  const int bt = blockIdx.x, ct = blockIdx.y, ez = blockIdx.z;
  const int e0 = ez * ne;
  outp += (size_t)ez * (size_t)B_ROWS * (size_t)K;

#pragma unroll
  for (int i = 0; i < 4; ++i) {
    int idx = t + (i << 9);  // 0..2047
    int rw = idx >> 3, e = idx & 7;
    scale_s[rw * 9 + e] = scales[(size_t)(bt * 256 + rw) * 8 + e];
  }

  // Stage bases: per wave 2 row-group blocks (1KB each) per 16KB unit.
  size_t abase[2], wbase[2];
#pragma unroll
  for (int i = 0; i < 2; ++i) {
    int g = w * 2 + i;
    abase[i] = (size_t)(bt * 256 + g * 16 + (l & 15)) * J + ((l >> 4) * 8);
    wbase[i] = (size_t)(ct * 256 + g * 16 + (l & 15)) * Kd + (size_t)e0 * J +
               ((l >> 4) * 8);
  }
  int s_acol = 0, s_wcol = 0, sjt = 0;  // stage-side counters (next tile)

  auto stageAll = [&](int nb) {
#pragma unroll
    for (int ks = 0; ks < 2; ++ks) {
      short* dA = &As[nb][ks][w * 2 * 512];
      gload16(inp + abase[0] + s_acol + ks * 32, dA);
      gload16(inp + abase[1] + s_acol + ks * 32, dA + 512);
      short* dW = &Wsm[nb][ks][w * 2 * 512];
      gload16(wT + wbase[0] + s_wcol + ks * 32, dW);
      gload16(wT + wbase[1] + s_wcol + ks * 32, dW + 512);
    }
    s_wcol += 64;
    if (++sjt == nj) { sjt = 0; s_acol = 0; } else { s_acol += 64; }
  };

  f32x4 acc[8][4];
#pragma unroll
  for (int fm = 0; fm < 8; ++fm)
#pragma unroll
    for (int fn = 0; fn < 4; ++fn) acc[fm][fn] = (f32x4){0.f, 0.f, 0.f, 0.f};

  bf16x8 fb0[4], fb1[4], fa0[4], fa1[4];

  // prologue: tile 0 fully staged into buf 0; full drain once (also
  // publishes scale_s). Then pre-read tile0's M0 operands.
  stageAll(0);
  __syncthreads();
  RD_B(fb0, &Wsm[0][0][0]);
  RD_A(fa0, &As[0][0][0], 0);

  int cjt = 0, cle = 0;  // compute-side counters
  for (int tp = 0; tp < nt; ++tp) {
    const int b = tp & 1, nb = b ^ 1;
    const bool more = (tp + 1 < nt);
    const short* A0 = &As[b][0][0];
    const short* A1 = &As[b][1][0];
    const short* W1 = &Wsm[b][1][0];

    if (more) stageAll(nb);   // whole next tile, ~3000 cyc before its drain

    RD_A(fa1, A0, 4);         // A(k0, m4-7)
    MM(0, fa0, fb0);          // M0
    RD_B(fb1, W1);            // B(k1)
    RD_A(fa0, A1, 0);         // A(k1, m0-3)
    MM(4, fa1, fb0);          // M1
    RD_A(fa1, A1, 4);         // A(k1, m4-7)
    MM(0, fa0, fb1);          // M2
    MM(4, fa1, fb1);          // M3

    // Horner boundary rescale at expert end (1 of nj tiles)
    if (++cjt == nj) {
      cjt = 0;
      int e = e0 + cle;
      ++cle;
#pragma unroll
      for (int fi = 0; fi < 8; ++fi) {
        int rbase = wm * 128 + fi * 16 + ((l >> 4) << 2);
#pragma unroll
        for (int rr = 0; rr < 4; ++rr) {
          float rv = scale_s[(rbase + rr) * 9 + e];
#pragma unroll
          for (int fn = 0; fn < 4; ++fn) acc[fi][fn][rr] *= rv;
        }
      }
    }

    asm volatile("s_waitcnt vmcnt(0)" ::: "memory");  // next tile staged
    asm volatile("s_barrier" ::: "memory");           // buf b reads all done
    if (more) {
      RD_B(fb0, &Wsm[nb][0][0]);   // next tile M0 operands
      RD_A(fa0, &As[nb][0][0], 0);
    }
  }

  // epilogue: raw fp32 partial store (bias/ELU fused downstream)
#pragma unroll
  for (int fi = 0; fi < 8; ++fi) {
#pragma unroll
    for (int rr = 0; rr < 4; ++rr) {
      int row = wm * 128 + fi * 16 + ((l >> 4) << 2) + rr;
      size_t orow = (size_t)(bt * 256 + row) * K + ct * 256;
#pragma unroll
      for (int fn = 0; fn < 4; ++fn) {
        int col = wn * 64 + fn * 16 + (l & 15);
        outp[orow + col] = acc[fi][fn][rr];
      }
    }
  }
}

// ---------------------------------------------------------------------------
// Final combine for layer 3 (4-way expert split, K=512, no activation):
//   out = p0+p1+p2+p3 + coeff@bias
// ---------------------------------------------------------------------------
__global__ __launch_bounds__(256) void combine4_k(
    const float* __restrict__ pb, const float* __restrict__ cf,
    const float* __restrict__ bias, float* __restrict__ out, int K) {
  size_t i4 = (size_t)blockIdx.x * 256 + threadIdx.x;
  size_t total = (size_t)B_ROWS * (size_t)K;
  size_t base = i4 * 4;
  if (base >= total) return;
  int row = (int)(base / (size_t)K);
  int col = (int)(base % (size_t)K);
  size_t s4 = total >> 2;  // partial stride in f32x4 units
  const f32x4* p4 = (const f32x4*)pb;
  f32x4 v = p4[i4] + p4[i4 + s4] + p4[i4 + 2 * s4] + p4[i4 + 3 * s4];
#pragma unroll
  for (int e = 0; e < 8; ++e) {
    float ce = cf[(size_t)row * 8 + e];
    f32x4 bv = *(const f32x4*)(bias + (size_t)e * K + col);
    v += ce * bv;
  }
  ((f32x4*)out)[i4] = v;
}

// ---------------------------------------------------------------------------
extern "C" void kernel_launch(void* const* d_in, const int* in_sizes, int n_in,
                              void* d_out, int out_size, void* d_ws, size_t ws_size,
                              hipStream_t stream) {
  const float* z   = (const float*)d_in[0];
  const float* c   = (const float*)d_in[1];
  const float* g0w = (const float*)d_in[2];
  const float* g0b = (const float*)d_in[3];
  const float* g1w = (const float*)d_in[4];
  const float* g1b = (const float*)d_in[5];
  const float* g2w = (const float*)d_in[6];
  const float* g2b = (const float*)d_in[7];
  const float* w0  = (const float*)d_in[8];
  const float* b0  = (const float*)d_in[9];
  const float* w1  = (const float*)d_in[10];
  const float* b1  = (const float*)d_in[11];
  const float* w2  = (const float*)d_in[12];
  const float* b2  = (const float*)d_in[13];
  const float* w3  = (const float*)d_in[14];
  const float* b3  = (const float*)d_in[15];

  char* ws = (char*)d_ws;
  size_t o = 0;
  auto alloc = [&](size_t bytes) {
    void* p = ws + o;
    o += (bytes + 255) & ~(size_t)255;
    return p;
  };
  ushort_t* wT0 = (ushort_t*)alloc((size_t)2560 * 1024 * 2);
  ushort_t* wT1 = (ushort_t*)alloc((size_t)8704 * 1024 * 2);
  ushort_t* wT2 = (ushort_t*)alloc((size_t)8704 * 1024 * 2);
  ushort_t* wT3 = (ushort_t*)alloc((size_t)8704 * 512 * 2);
  float*    cf   = (float*)alloc((size_t)B_ROWS * 8 * 4);
  float*    rat2 = (float*)alloc((size_t)B_ROWS * 8 * 4);
  float*    rat4 = (float*)alloc((size_t)B_ROWS * 8 * 4);
  ushort_t* inp  = (ushort_t*)alloc((size_t)B_ROWS * 1088 * 2);
  float*    pb   = (float*)alloc((size_t)2 * B_ROWS * 1024 * 4);  // partials

  dim3 tb(64, 16);
  transpose_k<<<dim3(1024 / 64, 2560 / 64), tb, 0, stream>>>(w0, wT0, 2560, 1024);
  transpose_k<<<dim3(1024 / 64, 8704 / 64), tb, 0, stream>>>(w1, wT1, 8704, 1024);
  transpose_k<<<dim3(1024 / 64, 8704 / 64), tb, 0, stream>>>(w2, wT2, 8704, 1024);
  transpose_k<<<dim3(512 / 64, 8704 / 64), tb, 0, stream>>>(w3, wT3, 8704, 512);

  gate_k<<<B_ROWS / 4, 128, 0, stream>>>(z, c, g0w, g0b, g1w, g1b, g2w, g2b,
                                         cf, rat2, rat4);

  float* p1v = pb + (size_t)B_ROWS * 1024;

  // layer 0: J=320, K=1024, 2-way expert split (ne=4), grid 32x4x2 = 256
  ln_concat_k<<<B_ROWS, 128, 0, stream>>>(z, c, nullptr, nullptr, nullptr,
                                          inp, 256, 320);
  moe_gemm_k<<<dim3(32, 4, 2), 512, 0, stream>>>(inp, wT0, rat2, pb, 320, 1024, 4);
  // layer 1: J=1088, K=1024 (ln fuses partial combine + b0-mix + elu)
  ln_concat_k<<<B_ROWS, 128, 0, stream>>>(z, pb, p1v, cf, b0, inp, 1024, 1088);
  moe_gemm_k<<<dim3(32, 4, 2), 512, 0, stream>>>(inp, wT1, rat2, pb, 1088, 1024, 4);
  // layer 2
  ln_concat_k<<<B_ROWS, 128, 0, stream>>>(z, pb, p1v, cf, b1, inp, 1024, 1088);
  moe_gemm_k<<<dim3(32, 4, 2), 512, 0, stream>>>(inp, wT2, rat2, pb, 1088, 1024, 4);
  // layer 3: J=1088, K=512, 4-way expert split (ne=2), grid 32x2x4 = 256
  ln_concat_k<<<B_ROWS, 128, 0, stream>>>(z, pb, p1v, cf, b2, inp, 1024, 1088);
  moe_gemm_k<<<dim3(32, 2, 4), 512, 0, stream>>>(inp, wT3, rat4, pb, 1088, 512, 2);
  combine4_k<<<(B_ROWS * 512) / 1024, 256, 0, stream>>>(pb, cf, b3,
                                                        (float*)d_out, 512);
}

// Round 8
// 740.643 us; speedup vs baseline: 1.3307x; 1.0311x over previous
//
#include <hip/hip_runtime.h>
#include <cstdint>
#include <cstddef>

// Problem constants (fixed by the reference)
#define B_ROWS 8192
#define E_EXP  8

typedef unsigned short ushort_t;
typedef short bf16x8 __attribute__((ext_vector_type(8)));
typedef float f32x4  __attribute__((ext_vector_type(4)));
typedef float f32x16 __attribute__((ext_vector_type(16)));

__device__ __forceinline__ ushort_t f2b(float f) {
  union { float f; unsigned int i; } v; v.f = f;
  unsigned int u = v.i;
  unsigned int r = (u + 0x7fffu + ((u >> 16) & 1u)) >> 16;
  return (ushort_t)r;
}
__device__ __forceinline__ float eluf(float x) {
  return x > 0.f ? x : (__expf(x) - 1.f);
}

// ---------------------------------------------------------------------------
// Weight transpose + fp32->bf16: w flat [R][C] -> wT [C][R] bf16.
// ---------------------------------------------------------------------------
__global__ void transpose_k(const float* __restrict__ src,
                            ushort_t* __restrict__ dst, int R, int C) {
  __shared__ ushort_t tile[64][65];
  int c0 = blockIdx.x * 64, r0 = blockIdx.y * 64;
  int x = threadIdx.x, y = threadIdx.y;
#pragma unroll
  for (int i = 0; i < 4; ++i)
    tile[y + 16 * i][x] = f2b(src[(size_t)(r0 + y + 16 * i) * C + c0 + x]);
  __syncthreads();
#pragma unroll
  for (int i = 0; i < 4; ++i)
    dst[(size_t)(c0 + y + 16 * i) * R + r0 + x] = tile[x][y + 16 * i];
}

// ---------------------------------------------------------------------------
// Gating MLP (pure fp32). Round 14: j-loops unrolled x4 with float4 LDS
// reads (was scalar-issue-bound, ~30us by budget subtraction). Emits:
//   coeff[b][e]  softmax probs
//   rat2[b][e]   2-way split {0-3},{4-7}: e in {3,7}: c_e; else c_e/c_{e+1}
//   rat4[b][e]   4-way split {0,1}..{6,7}: e odd: c_e; e even: c_e/c_{e+1}
// ---------------------------------------------------------------------------
__global__ __launch_bounds__(128) void gate_k(
    const float* __restrict__ z, const float* __restrict__ c,
    const float* __restrict__ g0w, const float* __restrict__ g0b,
    const float* __restrict__ g1w, const float* __restrict__ g1b,
    const float* __restrict__ g2w, const float* __restrict__ g2b,
    float* __restrict__ coeff, float* __restrict__ rat2,
    float* __restrict__ rat4) {
  __shared__ float xs[4][320];
  __shared__ float h1[4][128];
  __shared__ float h2[4][128];
  __shared__ float lg[4][8];
  __shared__ float pr[4][8];
  int t = threadIdx.x;
  int r0 = blockIdx.x * 4;
  for (int idx = t; idx < 4 * 320; idx += 128) {
    int r = idx / 320, j = idx % 320;
    xs[r][j] = (j < 64) ? z[(size_t)(r0 + r) * 64 + j]
                        : c[(size_t)(r0 + r) * 256 + j - 64];
  }
  __syncthreads();
  {
    float bb = g0b[t];
    float a0 = bb, a1 = bb, a2 = bb, a3 = bb;
    for (int j = 0; j < 320; j += 4) {
      float w0 = g0w[j * 128 + t];
      float w1 = g0w[(j + 1) * 128 + t];
      float w2 = g0w[(j + 2) * 128 + t];
      float w3 = g0w[(j + 3) * 128 + t];
      float4 x0 = *(const float4*)&xs[0][j];
      float4 x1 = *(const float4*)&xs[1][j];
      float4 x2 = *(const float4*)&xs[2][j];
      float4 x3 = *(const float4*)&xs[3][j];
      a0 += x0.x * w0 + x0.y * w1 + x0.z * w2 + x0.w * w3;
      a1 += x1.x * w0 + x1.y * w1 + x1.z * w2 + x1.w * w3;
      a2 += x2.x * w0 + x2.y * w1 + x2.z * w2 + x2.w * w3;
      a3 += x3.x * w0 + x3.y * w1 + x3.z * w2 + x3.w * w3;
    }
    h1[0][t] = eluf(a0); h1[1][t] = eluf(a1);
    h1[2][t] = eluf(a2); h1[3][t] = eluf(a3);
  }
  __syncthreads();
  {
    float bb = g1b[t];
    float a0 = bb, a1 = bb, a2 = bb, a3 = bb;
    for (int j = 0; j < 128; j += 4) {
      float w0 = g1w[j * 128 + t];
      float w1 = g1w[(j + 1) * 128 + t];
      float w2 = g1w[(j + 2) * 128 + t];
      float w3 = g1w[(j + 3) * 128 + t];
      float4 x0 = *(const float4*)&h1[0][j];
      float4 x1 = *(const float4*)&h1[1][j];
      float4 x2 = *(const float4*)&h1[2][j];
      float4 x3 = *(const float4*)&h1[3][j];
      a0 += x0.x * w0 + x0.y * w1 + x0.z * w2 + x0.w * w3;
      a1 += x1.x * w0 + x1.y * w1 + x1.z * w2 + x1.w * w3;
      a2 += x2.x * w0 + x2.y * w1 + x2.z * w2 + x2.w * w3;
      a3 += x3.x * w0 + x3.y * w1 + x3.z * w2 + x3.w * w3;
    }
    h2[0][t] = eluf(a0); h2[1][t] = eluf(a1);
    h2[2][t] = eluf(a2); h2[3][t] = eluf(a3);
  }
  __syncthreads();
  if (t < 32) {
    int r = t >> 3, e = t & 7;
    float a = g2b[e];
    for (int j = 0; j < 128; ++j) a += h2[r][j] * g2w[j * 8 + e];
    lg[r][e] = a;
  }
  __syncthreads();
  if (t < 32) {
    int r = t >> 3, e = t & 7;
    float mx = lg[r][0];
#pragma unroll
    for (int i = 1; i < 8; ++i) mx = fmaxf(mx, lg[r][i]);
    float s = 0.f;
#pragma unroll
    for (int i = 0; i < 8; ++i) s += __expf(lg[r][i] - mx);
    float p = __expf(lg[r][e] - mx) / s;
    coeff[(size_t)(r0 + r) * 8 + e] = p;
    pr[r][e] = p;
  }
  __syncthreads();
  if (t < 32) {
    int r = t >> 3, e = t & 7;
    float pe = pr[r][e];
    float ratio = (e < 7) ? pe / fmaxf(pr[r][e + 1], 1e-30f) : pe;
    rat2[(size_t)(r0 + r) * 8 + e] = (e == 3 || e == 7) ? pe : ratio;
    rat4[(size_t)(r0 + r) * 8 + e] = (e & 1) ? pe : ratio;
  }
}

// ---------------------------------------------------------------------------
// LayerNorm over concat([z_row, prev_row]) -> out [B][J] bf16.
//   p1 != null : prev = elu(p0 + p1 + sum_e cf[row,e]*bias[e,:])
//   p1 == null : prev = p0 raw (layer-0 path reading c)
// ---------------------------------------------------------------------------
__global__ __launch_bounds__(128) void ln_concat_k(
    const float* __restrict__ z, const float* __restrict__ p0,
    const float* __restrict__ p1, const float* __restrict__ cf,
    const float* __restrict__ bias, ushort_t* __restrict__ out,
    int Pw, int J) {
  int row = blockIdx.x, t = threadIdx.x;
  float vals[9];
  int n = (J + 127) >> 7;
  float cr[8];
  if (p1) {
#pragma unroll
    for (int e = 0; e < 8; ++e) cr[e] = cf[(size_t)row * 8 + e];
  }
  float s = 0.f, s2 = 0.f;
  for (int k = 0; k < n; ++k) {
    int i = t + (k << 7);
    float x = 0.f;
    if (i < J) {
      if (i < 64) {
        x = z[(size_t)row * 64 + i];
      } else if (p1) {
        int j = i - 64;
        float v = p0[(size_t)row * Pw + j] + p1[(size_t)row * Pw + j];
#pragma unroll
        for (int e = 0; e < 8; ++e) v += cr[e] * bias[(size_t)e * Pw + j];
        x = eluf(v);
      } else {
        x = p0[(size_t)row * Pw + i - 64];
      }
    }
    vals[k] = x; s += x; s2 += x * x;
  }
  for (int off = 32; off > 0; off >>= 1) {
    s += __shfl_down(s, off);
    s2 += __shfl_down(s2, off);
  }
  __shared__ float red[4];
  int wid = t >> 6, lane = t & 63;
  if (lane == 0) { red[wid * 2] = s; red[wid * 2 + 1] = s2; }
  __syncthreads();
  float S = red[0] + red[2], S2 = red[1] + red[3];
  float inv = 1.f / (float)J;
  float m = S * inv;
  float var = S2 * inv - m * m;
  float rstd = rsqrtf(var + 1e-5f);
  for (int k = 0; k < n; ++k) {
    int i = t + (k << 7);
    if (i < J) out[(size_t)row * J + i] = f2b((vals[k] - m) * rstd);
  }
}

// ---------------------------------------------------------------------------
// Fused MoE GEMM, round 14: round-3 schedule (verified best: 4-phase,
// counted vmcnt(4) twice/K-tile, 2 barriers/K-tile) with 32x32x16 MFMA.
//
// Rounds 4-6 post-mortem: three attempts to overlap the LDS and MFMA
// windows (lockstep barriers: neutral; 2blk/CU: -70%; reg-pipeline +
// burst staging: -13%) all failed — round-3 is this family's optimum at
// 5630 cyc/K-tile = MFMA 2484 + LDS ~3072 serial. This round shrinks the
// MFMA window instead of rearranging it: 32x32x16 frags run at 2382 vs
// 2075 TF (µbench) -> 2164-cyc window, and HALVE the MFMA instruction
// count (32 vs 64 per wave/K-tile), freeing issue slots that compete
// with ds_read issue. LDS bytes/read-counts are unchanged (24 b128).
//
// Fragment mapping (32x32x16, K-slice s in {0,1} per 32-col half):
//   A frag (R,s): row l&31 of rowgrp R, k = s*16 + (l>>5)*8 + j
//     addr = half_ks + (wm*8 + R*2 + ((l&31)>>4))*512 + (l&15)*8
//            + (s*2 + (l>>5))*128        [shorts]
//   W frag (C,s): same form, block (wn*4 + C*2 + ((l&31)>>4))
//   C/D: col = l&31, row = (reg&3) + 8*(reg>>2) + 4*(l>>5)  [m74/m101]
// acc[4][2] f32x16 = 128 VGPR (same as 16x16 version).
//
// 512 thr / 8 waves (2M x 4N), per-wave 128x64. LDS 128KB + scales 9KB
// -> 1 block/CU. Grid 256 = 1/CU via expert split: layers 0-2 ez=2
// (rat2, partials combined in ln_concat_k), layer 3 ez=4 (rat4,
// combine4_k). W offsets linear across experts; A col resets per expert.
// XCD = bt%8 (same-bt blocks co-XCD: A-panel L2-resident).
// ---------------------------------------------------------------------------
__device__ __forceinline__ void gload16(const void* g, void* l) {
  __builtin_amdgcn_global_load_lds(
      (const __attribute__((address_space(1))) void*)g,
      (__attribute__((address_space(3))) void*)l, 16, 0, 0);
}

__global__ __launch_bounds__(512, 2) void moe_gemm_k(
    const ushort_t* __restrict__ inp,   // [B][J] bf16 (LN'd concat)
    const ushort_t* __restrict__ wT,    // [K][E*J] bf16 (pre-transposed)
    const float* __restrict__ scales,   // [B][8] Horner boundary scales
    float* __restrict__ outp,           // [nez][B][K] fp32 partials
    int J, int K, int ne) {
  const int Kd = E_EXP * J;
  const int nj = J >> 6;        // BK=64 tiles per expert
  const int nt = ne * nj;       // total K-tiles for this block's expert range
  __shared__ short As[2][2][16 * 512];   // [buf][half][blk*512 + ...]  64KB
  __shared__ short Wsm[2][2][16 * 512];  // same                        64KB
  __shared__ float scale_s[256 * 9];     // [row][e] stride 9 (bank pad)

  const int t = threadIdx.x;
  const int w = t >> 6, l = t & 63;
  const int wm = w >> 2, wn = w & 3;     // 2M x 4N wave layout
  const int lr  = l & 31;                // row/col within 32-frag
  const int lh  = (l & 31) >> 4;         // 16-row block half
  const int lk  = l >> 5;                // k-half (0: k0-7, 1: k8-15)
  const int lro = (l & 15) * 8;          // within-block row offset (shorts)
  const int bt = blockIdx.x, ct = blockIdx.y, ez = blockIdx.z;
  const int e0 = ez * ne;
  outp += (size_t)ez * (size_t)B_ROWS * (size_t)K;

#pragma unroll
  for (int i = 0; i < 4; ++i) {
    int idx = t + (i << 9);  // 0..2047
    int rw = idx >> 3, e = idx & 7;
    scale_s[rw * 9 + e] = scales[(size_t)(bt * 256 + rw) * 8 + e];
  }

  // Stage bases: per wave 2 row-group blocks (1KB each) per 16KB half.
  size_t abase[2], wbase[2];
#pragma unroll
  for (int i = 0; i < 2; ++i) {
    int g = w * 2 + i;
    abase[i] = (size_t)(bt * 256 + g * 16 + (l & 15)) * J + ((l >> 4) * 8);
    wbase[i] = (size_t)(ct * 256 + g * 16 + (l & 15)) * Kd + (size_t)e0 * J +
               ((l >> 4) * 8);
  }
  int s_acol = 0, s_wcol = 0, sjt = 0;  // stage-side counters (next tile)

  auto stageA = [&](int nb, int ks) {
    short* d = &As[nb][ks][w * 2 * 512];
    gload16(inp + abase[0] + s_acol + ks * 32, d);
    gload16(inp + abase[1] + s_acol + ks * 32, d + 512);
  };
  auto stageW = [&](int nb, int ks) {
    short* d = &Wsm[nb][ks][w * 2 * 512];
    gload16(wT + wbase[0] + s_wcol + ks * 32, d);
    gload16(wT + wbase[1] + s_wcol + ks * 32, d + 512);
  };
  auto advance = [&]() {
    s_wcol += 64;
    if (++sjt == nj) { sjt = 0; s_acol = 0; } else { s_acol += 64; }
  };

  f32x16 acc[4][2];
#pragma unroll
  for (int R = 0; R < 4; ++R)
#pragma unroll
    for (int C = 0; C < 2; ++C)
#pragma unroll
      for (int q = 0; q < 16; ++q) acc[R][C][q] = 0.f;

  // frag readers
  auto rdA = [&](bf16x8* dst, const short* half, int s) {
#pragma unroll
    for (int R = 0; R < 4; ++R)
      dst[R] = *(const bf16x8*)(half + (wm * 8 + R * 2 + lh) * 512 + lro +
                                (s * 2 + lk) * 128);
  };
  auto rdW = [&](bf16x8(*dst)[2], const short* half) {
#pragma unroll
    for (int s = 0; s < 2; ++s)
#pragma unroll
      for (int C = 0; C < 2; ++C)
        dst[s][C] = *(const bf16x8*)(half + (wn * 4 + C * 2 + lh) * 512 + lro +
                                     (s * 2 + lk) * 128);
  };

#define MM8(AF, BF)                                                        \
  __builtin_amdgcn_s_setprio(1);                                           \
  _Pragma("unroll") for (int R = 0; R < 4; ++R)                            \
      _Pragma("unroll") for (int C = 0; C < 2; ++C) acc[R][C] =            \
          __builtin_amdgcn_mfma_f32_32x32x16_bf16(AF[R], BF[C],            \
                                                  acc[R][C], 0, 0, 0);     \
  __builtin_amdgcn_s_setprio(0);

  // prologue: tile 0 fully staged into buf 0; full drain once (also
  // publishes scale_s).
  stageA(0, 0); stageW(0, 0); stageA(0, 1); stageW(0, 1); advance();
  __syncthreads();

  int cjt = 0, cle = 0;  // compute-side counters
  for (int tp = 0; tp < nt; ++tp) {
    const int b = tp & 1, nb = b ^ 1;
    const bool more = (tp + 1 < nt);
    const short* A0 = &As[b][0][0];
    const short* A1 = &As[b][1][0];
    const short* W0 = &Wsm[b][0][0];
    const short* W1 = &Wsm[b][1][0];
    bf16x8 af[4], bf[2][2];

    // ---- phase 1: stage A'(0); read B(half0 s0+s1) + A(half0,s0); 8 MFMA
    if (more) stageA(nb, 0);
    rdW(bf, W0);
    rdA(af, A0, 0);
    MM8(af, bf[0]);
    // ---- phase 2: stage W'(0); read A(half0,s1); 8 MFMA; vmcnt(4); barrier
    if (more) stageW(nb, 0);
    rdA(af, A0, 1);
    MM8(af, bf[1]);
    if (more) asm volatile("s_waitcnt vmcnt(4)" ::: "memory");
    else      asm volatile("s_waitcnt vmcnt(0)" ::: "memory");
    asm volatile("s_barrier" ::: "memory");
    // ---- phase 3: stage A'(1); read B(half1) + A(half1,s0); 8 MFMA
    if (more) stageA(nb, 1);
    rdW(bf, W1);
    rdA(af, A1, 0);
    MM8(af, bf[0]);
    // ---- phase 4: stage W'(1); read A(half1,s1); 8 MFMA; boundary; barrier
    if (more) { stageW(nb, 1); advance(); }
    rdA(af, A1, 1);
    MM8(af, bf[1]);
    if (++cjt == nj) {
      cjt = 0;
      int e = e0 + cle;
      ++cle;
#pragma unroll
      for (int R = 0; R < 4; ++R) {
#pragma unroll
        for (int q = 0; q < 16; ++q) {
          int row = wm * 128 + R * 32 + (q & 3) + 8 * (q >> 2) + 4 * lk;
          float rv = scale_s[row * 9 + e];
          acc[R][0][q] *= rv;
          acc[R][1][q] *= rv;
        }
      }
    }
    if (more) asm volatile("s_waitcnt vmcnt(4)" ::: "memory");
    else      asm volatile("s_waitcnt vmcnt(0)" ::: "memory");
    asm volatile("s_barrier" ::: "memory");
  }

  // epilogue: raw fp32 partial store (bias/ELU fused downstream)
#pragma unroll
  for (int R = 0; R < 4; ++R) {
#pragma unroll
    for (int q = 0; q < 16; ++q) {
      int row = wm * 128 + R * 32 + (q & 3) + 8 * (q >> 2) + 4 * lk;
      size_t orow = (size_t)(bt * 256 + row) * K + ct * 256;
#pragma unroll
      for (int C = 0; C < 2; ++C)
        outp[orow + wn * 64 + C * 32 + lr] = acc[R][C][q];
    }
  }
}

// ---------------------------------------------------------------------------
// Final combine for layer 3 (4-way expert split, K=512, no activation):
//   out = p0+p1+p2+p3 + coeff@bias
// ---------------------------------------------------------------------------
__global__ __launch_bounds__(256) void combine4_k(
    const float* __restrict__ pb, const float* __restrict__ cf,
    const float* __restrict__ bias, float* __restrict__ out, int K) {
  size_t i4 = (size_t)blockIdx.x * 256 + threadIdx.x;
  size_t total = (size_t)B_ROWS * (size_t)K;
  size_t base = i4 * 4;
  if (base >= total) return;
  int row = (int)(base / (size_t)K);
  int col = (int)(base % (size_t)K);
  size_t s4 = total >> 2;  // partial stride in f32x4 units
  const f32x4* p4 = (const f32x4*)pb;
  f32x4 v = p4[i4] + p4[i4 + s4] + p4[i4 + 2 * s4] + p4[i4 + 3 * s4];
#pragma unroll
  for (int e = 0; e < 8; ++e) {
    float ce = cf[(size_t)row * 8 + e];
    f32x4 bv = *(const f32x4*)(bias + (size_t)e * K + col);
    v += ce * bv;
  }
  ((f32x4*)out)[i4] = v;
}

// ---------------------------------------------------------------------------
extern "C" void kernel_launch(void* const* d_in, const int* in_sizes, int n_in,
                              void* d_out, int out_size, void* d_ws, size_t ws_size,
                              hipStream_t stream) {
  const float* z   = (const float*)d_in[0];
  const float* c   = (const float*)d_in[1];
  const float* g0w = (const float*)d_in[2];
  const float* g0b = (const float*)d_in[3];
  const float* g1w = (const float*)d_in[4];
  const float* g1b = (const float*)d_in[5];
  const float* g2w = (const float*)d_in[6];
  const float* g2b = (const float*)d_in[7];
  const float* w0  = (const float*)d_in[8];
  const float* b0  = (const float*)d_in[9];
  const float* w1  = (const float*)d_in[10];
  const float* b1  = (const float*)d_in[11];
  const float* w2  = (const float*)d_in[12];
  const float* b2  = (const float*)d_in[13];
  const float* w3  = (const float*)d_in[14];
  const float* b3  = (const float*)d_in[15];

  char* ws = (char*)d_ws;
  size_t o = 0;
  auto alloc = [&](size_t bytes) {
    void* p = ws + o;
    o += (bytes + 255) & ~(size_t)255;
    return p;
  };
  ushort_t* wT0 = (ushort_t*)alloc((size_t)2560 * 1024 * 2);
  ushort_t* wT1 = (ushort_t*)alloc((size_t)8704 * 1024 * 2);
  ushort_t* wT2 = (ushort_t*)alloc((size_t)8704 * 1024 * 2);
  ushort_t* wT3 = (ushort_t*)alloc((size_t)8704 * 512 * 2);
  float*    cf   = (float*)alloc((size_t)B_ROWS * 8 * 4);
  float*    rat2 = (float*)alloc((size_t)B_ROWS * 8 * 4);
  float*    rat4 = (float*)alloc((size_t)B_ROWS * 8 * 4);
  ushort_t* inp  = (ushort_t*)alloc((size_t)B_ROWS * 1088 * 2);
  float*    pb   = (float*)alloc((size_t)2 * B_ROWS * 1024 * 4);  // partials

  dim3 tb(64, 16);
  transpose_k<<<dim3(1024 / 64, 2560 / 64), tb, 0, stream>>>(w0, wT0, 2560, 1024);
  transpose_k<<<dim3(1024 / 64, 8704 / 64), tb, 0, stream>>>(w1, wT1, 8704, 1024);
  transpose_k<<<dim3(1024 / 64, 8704 / 64), tb, 0, stream>>>(w2, wT2, 8704, 1024);
  transpose_k<<<dim3(512 / 64, 8704 / 64), tb, 0, stream>>>(w3, wT3, 8704, 512);

  gate_k<<<B_ROWS / 4, 128, 0, stream>>>(z, c, g0w, g0b, g1w, g1b, g2w, g2b,
                                         cf, rat2, rat4);

  float* p1v = pb + (size_t)B_ROWS * 1024;

  // layer 0: J=320, K=1024, 2-way expert split (ne=4), grid 32x4x2 = 256
  ln_concat_k<<<B_ROWS, 128, 0, stream>>>(z, c, nullptr, nullptr, nullptr,
                                          inp, 256, 320);
  moe_gemm_k<<<dim3(32, 4, 2), 512, 0, stream>>>(inp, wT0, rat2, pb, 320, 1024, 4);
  // layer 1: J=1088, K=1024 (ln fuses partial combine + b0-mix + elu)
  ln_concat_k<<<B_ROWS, 128, 0, stream>>>(z, pb, p1v, cf, b0, inp, 1024, 1088);
  moe_gemm_k<<<dim3(32, 4, 2), 512, 0, stream>>>(inp, wT1, rat2, pb, 1088, 1024, 4);
  // layer 2
  ln_concat_k<<<B_ROWS, 128, 0, stream>>>(z, pb, p1v, cf, b1, inp, 1024, 1088);
  moe_gemm_k<<<dim3(32, 4, 2), 512, 0, stream>>>(inp, wT2, rat2, pb, 1088, 1024, 4);
  // layer 3: J=1088, K=512, 4-way expert split (ne=2), grid 32x2x4 = 256
  ln_concat_k<<<B_ROWS, 128, 0, stream>>>(z, pb, p1v, cf, b2, inp, 1024, 1088);
  moe_gemm_k<<<dim3(32, 2, 4), 512, 0, stream>>>(inp, wT3, rat4, pb, 1088, 512, 2);
  combine4_k<<<(B_ROWS * 512) / 1024, 256, 0, stream>>>(pb, cf, b3,
                                                        (float*)d_out, 512);
}

// Round 9
// 693.149 us; speedup vs baseline: 1.4218x; 1.0685x over previous
//
#include <hip/hip_runtime.h>
#include <cstdint>
#include <cstddef>

// Problem constants (fixed by the reference)
#define B_ROWS 8192
#define E_EXP  8

typedef unsigned short ushort_t;
typedef short bf16x8 __attribute__((ext_vector_type(8)));
typedef float f32x4  __attribute__((ext_vector_type(4)));

__device__ __forceinline__ ushort_t f2b(float f) {
  union { float f; unsigned int i; } v; v.f = f;
  unsigned int u = v.i;
  unsigned int r = (u + 0x7fffu + ((u >> 16) & 1u)) >> 16;
  return (ushort_t)r;
}
__device__ __forceinline__ float eluf(float x) {
  return x > 0.f ? x : (__expf(x) - 1.f);
}

// ---------------------------------------------------------------------------
// Weight transpose + fp32->bf16: w flat [R][C] -> wT [C][R] bf16.
// ---------------------------------------------------------------------------
__global__ void transpose_k(const float* __restrict__ src,
                            ushort_t* __restrict__ dst, int R, int C) {
  __shared__ ushort_t tile[64][65];
  int c0 = blockIdx.x * 64, r0 = blockIdx.y * 64;
  int x = threadIdx.x, y = threadIdx.y;
#pragma unroll
  for (int i = 0; i < 4; ++i)
    tile[y + 16 * i][x] = f2b(src[(size_t)(r0 + y + 16 * i) * C + c0 + x]);
  __syncthreads();
#pragma unroll
  for (int i = 0; i < 4; ++i)
    dst[(size_t)(c0 + y + 16 * i) * R + r0 + x] = tile[x][y + 16 * i];
}

// ---------------------------------------------------------------------------
// Gating MLP (pure fp32), float4-unrolled j-loops. Emits:
//   coeff[b][e]  softmax probs
//   rat2[b][e]   2-way split {0-3},{4-7}: e in {3,7}: c_e; else c_e/c_{e+1}
//   rat4[b][e]   4-way split {0,1}..{6,7}: e odd: c_e; e even: c_e/c_{e+1}
// ---------------------------------------------------------------------------
__global__ __launch_bounds__(128) void gate_k(
    const float* __restrict__ z, const float* __restrict__ c,
    const float* __restrict__ g0w, const float* __restrict__ g0b,
    const float* __restrict__ g1w, const float* __restrict__ g1b,
    const float* __restrict__ g2w, const float* __restrict__ g2b,
    float* __restrict__ coeff, float* __restrict__ rat2,
    float* __restrict__ rat4) {
  __shared__ float xs[4][320];
  __shared__ float h1[4][128];
  __shared__ float h2[4][128];
  __shared__ float lg[4][8];
  __shared__ float pr[4][8];
  int t = threadIdx.x;
  int r0 = blockIdx.x * 4;
  for (int idx = t; idx < 4 * 320; idx += 128) {
    int r = idx / 320, j = idx % 320;
    xs[r][j] = (j < 64) ? z[(size_t)(r0 + r) * 64 + j]
                        : c[(size_t)(r0 + r) * 256 + j - 64];
  }
  __syncthreads();
  {
    float bb = g0b[t];
    float a0 = bb, a1 = bb, a2 = bb, a3 = bb;
    for (int j = 0; j < 320; j += 4) {
      float w0 = g0w[j * 128 + t];
      float w1 = g0w[(j + 1) * 128 + t];
      float w2 = g0w[(j + 2) * 128 + t];
      float w3 = g0w[(j + 3) * 128 + t];
      float4 x0 = *(const float4*)&xs[0][j];
      float4 x1 = *(const float4*)&xs[1][j];
      float4 x2 = *(const float4*)&xs[2][j];
      float4 x3 = *(const float4*)&xs[3][j];
      a0 += x0.x * w0 + x0.y * w1 + x0.z * w2 + x0.w * w3;
      a1 += x1.x * w0 + x1.y * w1 + x1.z * w2 + x1.w * w3;
      a2 += x2.x * w0 + x2.y * w1 + x2.z * w2 + x2.w * w3;
      a3 += x3.x * w0 + x3.y * w1 + x3.z * w2 + x3.w * w3;
    }
    h1[0][t] = eluf(a0); h1[1][t] = eluf(a1);
    h1[2][t] = eluf(a2); h1[3][t] = eluf(a3);
  }
  __syncthreads();
  {
    float bb = g1b[t];
    float a0 = bb, a1 = bb, a2 = bb, a3 = bb;
    for (int j = 0; j < 128; j += 4) {
      float w0 = g1w[j * 128 + t];
      float w1 = g1w[(j + 1) * 128 + t];
      float w2 = g1w[(j + 2) * 128 + t];
      float w3 = g1w[(j + 3) * 128 + t];
      float4 x0 = *(const float4*)&h1[0][j];
      float4 x1 = *(const float4*)&h1[1][j];
      float4 x2 = *(const float4*)&h1[2][j];
      float4 x3 = *(const float4*)&h1[3][j];
      a0 += x0.x * w0 + x0.y * w1 + x0.z * w2 + x0.w * w3;
      a1 += x1.x * w0 + x1.y * w1 + x1.z * w2 + x1.w * w3;
      a2 += x2.x * w0 + x2.y * w1 + x2.z * w2 + x2.w * w3;
      a3 += x3.x * w0 + x3.y * w1 + x3.z * w2 + x3.w * w3;
    }
    h2[0][t] = eluf(a0); h2[1][t] = eluf(a1);
    h2[2][t] = eluf(a2); h2[3][t] = eluf(a3);
  }
  __syncthreads();
  if (t < 32) {
    int r = t >> 3, e = t & 7;
    float a = g2b[e];
    for (int j = 0; j < 128; ++j) a += h2[r][j] * g2w[j * 8 + e];
    lg[r][e] = a;
  }
  __syncthreads();
  if (t < 32) {
    int r = t >> 3, e = t & 7;
    float mx = lg[r][0];
#pragma unroll
    for (int i = 1; i < 8; ++i) mx = fmaxf(mx, lg[r][i]);
    float s = 0.f;
#pragma unroll
    for (int i = 0; i < 8; ++i) s += __expf(lg[r][i] - mx);
    float p = __expf(lg[r][e] - mx) / s;
    coeff[(size_t)(r0 + r) * 8 + e] = p;
    pr[r][e] = p;
  }
  __syncthreads();
  if (t < 32) {
    int r = t >> 3, e = t & 7;
    float pe = pr[r][e];
    float ratio = (e < 7) ? pe / fmaxf(pr[r][e + 1], 1e-30f) : pe;
    rat2[(size_t)(r0 + r) * 8 + e] = (e == 3 || e == 7) ? pe : ratio;
    rat4[(size_t)(r0 + r) * 8 + e] = (e & 1) ? pe : ratio;
  }
}

// ---------------------------------------------------------------------------
// LayerNorm over concat([z_row, prev_row]) -> out [B][J] bf16.
//   p1 != null : prev = elu(p0 + p1 + sum_e cf[row,e]*bias[e,:])
//   p1 == null : prev = p0 raw (layer-0 path reading c)
// ---------------------------------------------------------------------------
__global__ __launch_bounds__(128) void ln_concat_k(
    const float* __restrict__ z, const float* __restrict__ p0,
    const float* __restrict__ p1, const float* __restrict__ cf,
    const float* __restrict__ bias, ushort_t* __restrict__ out,
    int Pw, int J) {
  int row = blockIdx.x, t = threadIdx.x;
  float vals[9];
  int n = (J + 127) >> 7;
  float cr[8];
  if (p1) {
#pragma unroll
    for (int e = 0; e < 8; ++e) cr[e] = cf[(size_t)row * 8 + e];
  }
  float s = 0.f, s2 = 0.f;
  for (int k = 0; k < n; ++k) {
    int i = t + (k << 7);
    float x = 0.f;
    if (i < J) {
      if (i < 64) {
        x = z[(size_t)row * 64 + i];
      } else if (p1) {
        int j = i - 64;
        float v = p0[(size_t)row * Pw + j] + p1[(size_t)row * Pw + j];
#pragma unroll
        for (int e = 0; e < 8; ++e) v += cr[e] * bias[(size_t)e * Pw + j];
        x = eluf(v);
      } else {
        x = p0[(size_t)row * Pw + i - 64];
      }
    }
    vals[k] = x; s += x; s2 += x * x;
  }
  for (int off = 32; off > 0; off >>= 1) {
    s += __shfl_down(s, off);
    s2 += __shfl_down(s2, off);
  }
  __shared__ float red[4];
  int wid = t >> 6, lane = t & 63;
  if (lane == 0) { red[wid * 2] = s; red[wid * 2 + 1] = s2; }
  __syncthreads();
  float S = red[0] + red[2], S2 = red[1] + red[3];
  float inv = 1.f / (float)J;
  float m = S * inv;
  float var = S2 * inv - m * m;
  float rstd = rsqrtf(var + 1e-5f);
  for (int k = 0; k < n; ++k) {
    int i = t + (k << 7);
    if (i < J) out[(size_t)row * J + i] = f2b((vals[k] - m) * rstd);
  }
}

// ---------------------------------------------------------------------------
// Fused MoE GEMM, round 15: 16 WAVES / CU (4 per SIMD) on the verified
// 4-phase counted-vmcnt schedule.
//
// Round-7 post-mortem: 32x32 MFMA neutral (VALUBusy 16.6->11.7 but time
// unchanged) -> not issue/rate-bound. Per-K-tile 5718 cyc ~= MFMA 2066 +
// LDS 2300 + writes 500 + VALU — the pipes run as a serial SUM within one
// barrier-synced 8-wave block, and 3 schedule rearrangements failed to
// overlap them. Last untested mechanism: wave-level TLP (m114: waves
// co-issue to MFMA/LDS pipes, time ~= max) — needs 4 waves/SIMD of
// desynchronized work; round-5's 2-block probe was confounded (128² tile,
// coarse schedule). This round: same 256² tile / BK=64 / blocked
// conflict-free LDS / per-phase 1-unit staging / vmcnt counted / 2
// barriers per K-tile — but 1024 thr, 16 waves, 4M x 4N, per-wave 64x64
// (acc 64 VGPR; <=128 VGPR for 4 waves/SIMD). LDS reads rise to 256
// b128/K-tile (+33%) — the bet is TLP converts serial-sum into overlap.
//
// vmcnt proof (per-wave counters, 1 gload16 per wave per phase):
//   ph1 stage A'(ks0), ph2 stage W'(ks0), ph3 stage A'(ks1), ph4 W'(ks1).
//   end-ph2: outstanding <= {prev ph3, prev ph4, cur ph1, cur ph2};
//     vmcnt(2) drains prev ph3/ph4 = THIS tile's ks1 units before ph3 reads.
//   end-ph4: vmcnt(2) drains cur ph1/ph2 = next tile's ks0 units. Last
//   tile stages nothing -> vmcnt(0) at both points.
// LDS 128KB + scales 9KB -> 1 block/CU. Grid 256 = 1/CU via expert split:
// layers 0-2 ez=2 (rat2, partials combined in ln_concat_k), layer 3 ez=4
// (rat4, combine4_k). W offsets linear across experts; A col resets per
// expert. XCD = bt%8 (same-bt blocks co-XCD: A-panel L2-resident).
// ---------------------------------------------------------------------------
__device__ __forceinline__ void gload16(const void* g, void* l) {
  __builtin_amdgcn_global_load_lds(
      (const __attribute__((address_space(1))) void*)g,
      (__attribute__((address_space(3))) void*)l, 16, 0, 0);
}

__global__ __launch_bounds__(1024, 1) void moe_gemm_k(
    const ushort_t* __restrict__ inp,   // [B][J] bf16 (LN'd concat)
    const ushort_t* __restrict__ wT,    // [K][E*J] bf16 (pre-transposed)
    const float* __restrict__ scales,   // [B][8] Horner boundary scales
    float* __restrict__ outp,           // [nez][B][K] fp32 partials
    int J, int K, int ne) {
  const int Kd = E_EXP * J;
  const int nj = J >> 6;        // BK=64 tiles per expert
  const int nt = ne * nj;       // total K-tiles for this block's expert range
  __shared__ short As[2][2][16 * 512];   // [buf][ks][blk*512 + l*8]  64KB
  __shared__ short Wsm[2][2][16 * 512];  // same                      64KB
  __shared__ float scale_s[256 * 9];     // [row][e] stride 9 (bank pad)

  const int t = threadIdx.x;
  const int w = t >> 6, l = t & 63;      // 16 waves
  const int wm = w >> 2, wn = w & 3;     // 4M x 4N wave layout, 64x64/wave
  const int bt = blockIdx.x, ct = blockIdx.y, ez = blockIdx.z;
  const int e0 = ez * ne;
  outp += (size_t)ez * (size_t)B_ROWS * (size_t)K;

#pragma unroll
  for (int i = 0; i < 2; ++i) {
    int idx = t + (i << 10);  // 0..2047
    int rw = idx >> 3, e = idx & 7;
    scale_s[rw * 9 + e] = scales[(size_t)(bt * 256 + rw) * 8 + e];
  }

  // Stage bases: wave w owns LDS block w (16 rows) of each 16KB unit.
  size_t abase = (size_t)(bt * 256 + w * 16 + (l & 15)) * J + ((l >> 4) * 8);
  size_t wbase = (size_t)(ct * 256 + w * 16 + (l & 15)) * Kd +
                 (size_t)e0 * J + ((l >> 4) * 8);
  int s_acol = 0, s_wcol = 0, sjt = 0;  // stage-side counters (next tile)

  auto stageA = [&](int nb, int ks) {
    gload16(inp + abase + s_acol + ks * 32, &As[nb][ks][w * 512]);
  };
  auto stageW = [&](int nb, int ks) {
    gload16(wT + wbase + s_wcol + ks * 32, &Wsm[nb][ks][w * 512]);
  };
  auto advance = [&]() {
    s_wcol += 64;
    if (++sjt == nj) { sjt = 0; s_acol = 0; } else { s_acol += 64; }
  };

  f32x4 acc[4][4];  // [row-frag q][col-frag fn]
#pragma unroll
  for (int q = 0; q < 4; ++q)
#pragma unroll
    for (int fn = 0; fn < 4; ++fn) acc[q][fn] = (f32x4){0.f, 0.f, 0.f, 0.f};

#define RDB(ks_)                                                           \
  _Pragma("unroll") for (int fn = 0; fn < 4; ++fn) bf[fn] =                \
      *(const bf16x8*)(&Wsm[b][ks_][(wn * 4 + fn) * 512 + l * 8]);

#define RDA2(d0, d1, ks_, q0)                                              \
  d0 = *(const bf16x8*)(&As[b][ks_][(wm * 4 + (q0)) * 512 + l * 8]);       \
  d1 = *(const bf16x8*)(&As[b][ks_][(wm * 4 + (q0) + 1) * 512 + l * 8]);

#define MM2(q0, a0_, a1_)                                                  \
  __builtin_amdgcn_s_setprio(1);                                           \
  _Pragma("unroll") for (int fn = 0; fn < 4; ++fn) {                       \
    acc[(q0)][fn] = __builtin_amdgcn_mfma_f32_16x16x32_bf16(               \
        a0_, bf[fn], acc[(q0)][fn], 0, 0, 0);                              \
    acc[(q0) + 1][fn] = __builtin_amdgcn_mfma_f32_16x16x32_bf16(           \
        a1_, bf[fn], acc[(q0) + 1][fn], 0, 0, 0);                          \
  }                                                                        \
  __builtin_amdgcn_s_setprio(0);

  // prologue: tile 0 fully staged into buf 0 (4 units); full drain once
  // (also publishes scale_s).
  stageA(0, 0); stageW(0, 0); stageA(0, 1); stageW(0, 1); advance();
  __syncthreads();

  int cjt = 0, cle = 0;  // compute-side counters
  for (int tp = 0; tp < nt; ++tp) {
    const int b = tp & 1, nb = b ^ 1;
    const bool more = (tp + 1 < nt);
    bf16x8 bf[4], a0, a1;

    // ---- phase 1: stage A'(ks0); read B(ks0) + A(ks0,q0-1); 8 MFMA
    if (more) stageA(nb, 0);
    RDB(0);
    RDA2(a0, a1, 0, 0);
    MM2(0, a0, a1);
    // ---- phase 2: stage W'(ks0); read A(ks0,q2-3); 8 MFMA; vmcnt; barrier
    if (more) stageW(nb, 0);
    RDA2(a0, a1, 0, 2);
    MM2(2, a0, a1);
    if (more) asm volatile("s_waitcnt vmcnt(2)" ::: "memory");
    else      asm volatile("s_waitcnt vmcnt(0)" ::: "memory");
    asm volatile("s_barrier" ::: "memory");
    // ---- phase 3: stage A'(ks1); read B(ks1) + A(ks1,q0-1); 8 MFMA
    if (more) stageA(nb, 1);
    RDB(1);
    RDA2(a0, a1, 1, 0);
    MM2(0, a0, a1);
    // ---- phase 4: stage W'(ks1); read A(ks1,q2-3); 8 MFMA; boundary;
    //               vmcnt; barrier
    if (more) { stageW(nb, 1); advance(); }
    RDA2(a0, a1, 1, 2);
    MM2(2, a0, a1);
    if (++cjt == nj) {
      cjt = 0;
      int e = e0 + cle;
      ++cle;
#pragma unroll
      for (int q = 0; q < 4; ++q) {
        int rbase = wm * 64 + q * 16 + ((l >> 4) << 2);
#pragma unroll
        for (int rr = 0; rr < 4; ++rr) {
          float rv = scale_s[(rbase + rr) * 9 + e];
#pragma unroll
          for (int fn = 0; fn < 4; ++fn) acc[q][fn][rr] *= rv;
        }
      }
    }
    if (more) asm volatile("s_waitcnt vmcnt(2)" ::: "memory");
    else      asm volatile("s_waitcnt vmcnt(0)" ::: "memory");
    asm volatile("s_barrier" ::: "memory");
  }

  // epilogue: raw fp32 partial store (bias/ELU fused downstream)
#pragma unroll
  for (int q = 0; q < 4; ++q) {
#pragma unroll
    for (int rr = 0; rr < 4; ++rr) {
      int row = wm * 64 + q * 16 + ((l >> 4) << 2) + rr;
      size_t orow = (size_t)(bt * 256 + row) * K + ct * 256;
#pragma unroll
      for (int fn = 0; fn < 4; ++fn) {
        int col = wn * 64 + fn * 16 + (l & 15);
        outp[orow + col] = acc[q][fn][rr];
      }
    }
  }
}

// ---------------------------------------------------------------------------
// Final combine for layer 3 (4-way expert split, K=512, no activation):
//   out = p0+p1+p2+p3 + coeff@bias
// ---------------------------------------------------------------------------
__global__ __launch_bounds__(256) void combine4_k(
    const float* __restrict__ pb, const float* __restrict__ cf,
    const float* __restrict__ bias, float* __restrict__ out, int K) {
  size_t i4 = (size_t)blockIdx.x * 256 + threadIdx.x;
  size_t total = (size_t)B_ROWS * (size_t)K;
  size_t base = i4 * 4;
  if (base >= total) return;
  int row = (int)(base / (size_t)K);
  int col = (int)(base % (size_t)K);
  size_t s4 = total >> 2;  // partial stride in f32x4 units
  const f32x4* p4 = (const f32x4*)pb;
  f32x4 v = p4[i4] + p4[i4 + s4] + p4[i4 + 2 * s4] + p4[i4 + 3 * s4];
#pragma unroll
  for (int e = 0; e < 8; ++e) {
    float ce = cf[(size_t)row * 8 + e];
    f32x4 bv = *(const f32x4*)(bias + (size_t)e * K + col);
    v += ce * bv;
  }
  ((f32x4*)out)[i4] = v;
}

// ---------------------------------------------------------------------------
extern "C" void kernel_launch(void* const* d_in, const int* in_sizes, int n_in,
                              void* d_out, int out_size, void* d_ws, size_t ws_size,
                              hipStream_t stream) {
  const float* z   = (const float*)d_in[0];
  const float* c   = (const float*)d_in[1];
  const float* g0w = (const float*)d_in[2];
  const float* g0b = (const float*)d_in[3];
  const float* g1w = (const float*)d_in[4];
  const float* g1b = (const float*)d_in[5];
  const float* g2w = (const float*)d_in[6];
  const float* g2b = (const float*)d_in[7];
  const float* w0  = (const float*)d_in[8];
  const float* b0  = (const float*)d_in[9];
  const float* w1  = (const float*)d_in[10];
  const float* b1  = (const float*)d_in[11];
  const float* w2  = (const float*)d_in[12];
  const float* b2  = (const float*)d_in[13];
  const float* w3  = (const float*)d_in[14];
  const float* b3  = (const float*)d_in[15];

  char* ws = (char*)d_ws;
  size_t o = 0;
  auto alloc = [&](size_t bytes) {
    void* p = ws + o;
    o += (bytes + 255) & ~(size_t)255;
    return p;
  };
  ushort_t* wT0 = (ushort_t*)alloc((size_t)2560 * 1024 * 2);
  ushort_t* wT1 = (ushort_t*)alloc((size_t)8704 * 1024 * 2);
  ushort_t* wT2 = (ushort_t*)alloc((size_t)8704 * 1024 * 2);
  ushort_t* wT3 = (ushort_t*)alloc((size_t)8704 * 512 * 2);
  float*    cf   = (float*)alloc((size_t)B_ROWS * 8 * 4);
  float*    rat2 = (float*)alloc((size_t)B_ROWS * 8 * 4);
  float*    rat4 = (float*)alloc((size_t)B_ROWS * 8 * 4);
  ushort_t* inp  = (ushort_t*)alloc((size_t)B_ROWS * 1088 * 2);
  float*    pb   = (float*)alloc((size_t)2 * B_ROWS * 1024 * 4);  // partials

  dim3 tb(64, 16);
  transpose_k<<<dim3(1024 / 64, 2560 / 64), tb, 0, stream>>>(w0, wT0, 2560, 1024);
  transpose_k<<<dim3(1024 / 64, 8704 / 64), tb, 0, stream>>>(w1, wT1, 8704, 1024);
  transpose_k<<<dim3(1024 / 64, 8704 / 64), tb, 0, stream>>>(w2, wT2, 8704, 1024);
  transpose_k<<<dim3(512 / 64, 8704 / 64), tb, 0, stream>>>(w3, wT3, 8704, 512);

  gate_k<<<B_ROWS / 4, 128, 0, stream>>>(z, c, g0w, g0b, g1w, g1b, g2w, g2b,
                                         cf, rat2, rat4);

  float* p1v = pb + (size_t)B_ROWS * 1024;

  // layer 0: J=320, K=1024, 2-way expert split (ne=4), grid 32x4x2 = 256
  ln_concat_k<<<B_ROWS, 128, 0, stream>>>(z, c, nullptr, nullptr, nullptr,
                                          inp, 256, 320);
  moe_gemm_k<<<dim3(32, 4, 2), 1024, 0, stream>>>(inp, wT0, rat2, pb, 320, 1024, 4);
  // layer 1: J=1088, K=1024 (ln fuses partial combine + b0-mix + elu)
  ln_concat_k<<<B_ROWS, 128, 0, stream>>>(z, pb, p1v, cf, b0, inp, 1024, 1088);
  moe_gemm_k<<<dim3(32, 4, 2), 1024, 0, stream>>>(inp, wT1, rat2, pb, 1088, 1024, 4);
  // layer 2
  ln_concat_k<<<B_ROWS, 128, 0, stream>>>(z, pb, p1v, cf, b1, inp, 1024, 1088);
  moe_gemm_k<<<dim3(32, 4, 2), 1024, 0, stream>>>(inp, wT2, rat2, pb, 1088, 1024, 4);
  // layer 3: J=1088, K=512, 4-way expert split (ne=2), grid 32x2x4 = 256
  ln_concat_k<<<B_ROWS, 128, 0, stream>>>(z, pb, p1v, cf, b2, inp, 1024, 1088);
  moe_gemm_k<<<dim3(32, 2, 4), 1024, 0, stream>>>(inp, wT3, rat4, pb, 1088, 512, 2);
  combine4_k<<<(B_ROWS * 512) / 1024, 256, 0, stream>>>(pb, cf, b3,
                                                        (float*)d_out, 512);
}